// Round 8
// baseline (92.195 us; speedup 1.0000x reference)
//
#include <hip/hip_runtime.h>

// QuantumLayer — ROUND-8 DIAGNOSTIC: byte-identical algorithm to round 6
// (best: 75.7us bench), but the whole per-element phase runs TWICE (identical
// work, identical output). Purpose: qmain has been invisible in rocprof since
// r4 (the harness's 41us d_ws-fill dispatches occupy the top-5; qmain < 41us).
// At ~2x duration qmain becomes the top dispatch and we finally get VALUBusy /
// MfmaUtil / VGPR_Count / WRITE_SIZE for the current structure, plus dur/2 as
// a direct measurement of true qmain time. Graph-capture-safe: same work every
// call; rep 2 recomputes from unchanged d_in and rewrites identical d_out.

typedef _Float16 half8  __attribute__((ext_vector_type(8)));
typedef float    float4v __attribute__((ext_vector_type(4)));
typedef unsigned int uint2v __attribute__((ext_vector_type(2)));
typedef unsigned int uint4v __attribute__((ext_vector_type(4)));

#define MEMFENCE() __asm__ volatile("" ::: "memory")

__device__ __forceinline__ unsigned pk2(float a, float b) {
  auto v = __builtin_amdgcn_cvt_pkrtz(a, b);
  return __builtin_bit_cast(unsigned, v);
}
__device__ __forceinline__ float rdlane(float v, int l) {
  return __builtin_bit_cast(float, __builtin_amdgcn_readlane(__builtin_bit_cast(int, v), l));
}
__device__ __forceinline__ unsigned sw8u(unsigned v) {
  return (unsigned)__builtin_amdgcn_mov_dpp((int)v, 0x128, 0xf, 0xf, false);
}
__device__ __forceinline__ float sw8f(float v) {
  return __builtin_bit_cast(float,
      __builtin_amdgcn_mov_dpp(__builtin_bit_cast(int, v), 0x128, 0xf, 0xf, false));
}
__device__ __forceinline__ int tauf(int l) {
  int y = l ^ (((l >> 3) & 1) << 2);
  y ^= ((y >> 2) & 1) << 1;
  y ^= (y >> 1) & 1;
  return y;
}

__launch_bounds__(256, 2)
__global__ void qmain(const float* __restrict__ x, const float* __restrict__ w,
                      float* __restrict__ out) {
  __shared__ __align__(16) unsigned char smem[32768];
  const int tid = threadIdx.x;
  const int lane = tid & 63, wv = tid >> 6;
  const int quad = lane >> 4, n = lane & 15;

  // ---- gate B-fragments (wave wv -> layer wv) ----
  {
    const int t = wv;
    int mr = n ^ ((n >> 1) & 1);
    mr ^= ((mr >> 2) & 1) << 1;
    mr ^= ((mr >> 3) & 1) << 2;
    float cS[8], sS[8], zcS[8], zsS[8];
#pragma unroll
    for (int qq = 0; qq < 8; ++qq) {
      float th = w[(t * 8 + qq) * 2 + 0];
      float tz = w[(t * 8 + qq) * 2 + 1];
      __sincosf(0.5f * th, &sS[qq], &cS[qq]);
      __sincosf(0.5f * tz, &zsS[qq], &zcS[qq]);
    }
    union { _Float16 h[8]; half8 v; } bLR, bLI, bRR, bRI;
#pragma unroll
    for (int ci = 0; ci < 4; ++ci) {
      const int kp = quad * 4 + ci;
      float hr = 1.f, hi = 0.f;
#pragma unroll
      for (int j = 0; j < 4; ++j) {
        int rb = (mr >> (3 - j)) & 1, cb = (kp >> (3 - j)) & 1;
        float ryv = (rb == cb) ? cS[j] : (rb ? sS[j] : -sS[j]);
        float ar = zcS[j] * ryv;
        float ai = (rb ? zsS[j] : -zsS[j]) * ryv;
        float nr = hr * ar - hi * ai, ni = hr * ai + hi * ar;
        hr = nr; hi = ni;
      }
      bLR.h[2 * ci] = (_Float16)hr;  bLR.h[2 * ci + 1] = (_Float16)(-hi);
      bLI.h[2 * ci] = (_Float16)hi;  bLI.h[2 * ci + 1] = (_Float16)hr;
      int yk = tauf(kp);
      float wr = 1.f, wi = 0.f;
#pragma unroll
      for (int j = 0; j < 4; ++j) {
        int rb = (n >> (3 - j)) & 1, cb = (yk >> (3 - j)) & 1;
        float ryv = (rb == cb) ? cS[4 + j] : (rb ? sS[4 + j] : -sS[4 + j]);
        float ar = zcS[4 + j] * ryv;
        float ai = (rb ? zsS[4 + j] : -zsS[4 + j]) * ryv;
        float nr = wr * ar - wi * ai, ni = wr * ai + wi * ar;
        wr = nr; wi = ni;
      }
      bRR.h[2 * ci] = (_Float16)wr;  bRR.h[2 * ci + 1] = (_Float16)(-wi);
      bRI.h[2 * ci] = (_Float16)wi;  bRI.h[2 * ci + 1] = (_Float16)wr;
    }
    half8* FB = (half8*)smem;
    FB[(t * 4 + 0) * 64 + lane] = bLR.v;
    FB[(t * 4 + 1) * 64 + lane] = bLI.v;
    FB[(t * 4 + 2) * 64 + lane] = bRR.v;
    FB[(t * 4 + 3) * 64 + lane] = bRI.v;
  }
  __syncthreads();
  half8 BLR[4], BLI[4], BRR[4], BRI[4];
#pragma unroll
  for (int t = 0; t < 4; ++t) {
    const half8* FB = (const half8*)smem;
    BLR[t] = FB[(t * 4 + 0) * 64 + lane];
    BLI[t] = FB[(t * 4 + 1) * 64 + lane];
    BRR[t] = FB[(t * 4 + 2) * 64 + lane];
    BRI[t] = FB[(t * 4 + 3) * 64 + lane];
  }
  __syncthreads();

  half8 sf[8];
#pragma unroll
  for (int c = 0; c < 8; ++c) {
    union { _Float16 h[8]; half8 v; } sg;
#pragma unroll
    for (int jj = 0; jj < 8; ++jj) {
      int u = (quad & 1) * 8 + jj;
      int y = tauf(2 * c + (quad >> 1));
      float sv = 0.f;
      if (n < 8) {
        int bit = (n < 4) ? ((u >> (3 - n)) & 1) : ((y >> (7 - n)) & 1);
        sv = bit ? -1.f : 1.f;
      }
      sg.h[jj] = (_Float16)sv;
    }
    sf[c] = sg.v;
  }

  unsigned char* smp = smem + wv * 8192;
  const unsigned pWg = (unsigned)(2 * n + (quad >> 1));
  const unsigned pWlo = (unsigned)((quad & 1) * 8);
  const int e0 = (blockIdx.x * 4 + wv) * 32;
  const float4v zz = {0.f, 0.f, 0.f, 0.f};
  const int ytau = tauf(n);

  const float* xp = x + (size_t)e0 * 8;
  float x0 = xp[lane], x1 = xp[64 + lane], x2 = xp[128 + lane], x3 = xp[192 + lane];
  float c0, s0, c1, s1, c2, s2, c3, s3;
  __sincosf(0.5f * x0, &s0, &c0);
  __sincosf(0.5f * x1, &s1, &c1);
  __sincosf(0.5f * x2, &s2, &c2);
  __sincosf(0.5f * x3, &s3, &c3);

#pragma clang loop unroll(disable)
  for (int rep = 0; rep < 2; ++rep) {   // DIAGNOSTIC: identical work twice
    for (int g = 0; g < 2; ++g) {
      const int base = e0 + g * 16;
      const float CA = g ? c2 : c0, SA = g ? s2 : s0;
      const float CB = g ? c3 : c1, SB = g ? s3 : s1;

#pragma unroll
      for (int i = 0; i < 4; ++i) {   // ILP4: elements e = 4i+h
        uint4v st[4];
#pragma unroll
        for (int h = 0; h < 4; ++h) {
          const int e = 4 * i + h;
          const float cs = (e < 8) ? CA : CB;
          const float sn = (e < 8) ? SA : SB;
          const int lb = (e & 7) * 8;
          float cq[8], sq[8];
#pragma unroll
          for (int q = 0; q < 8; ++q) { cq[q] = rdlane(cs, lb + q); sq[q] = rdlane(sn, lb + q); }
          float f0 = (quad & 2) ? sq[0] : cq[0];
          float f1 = (quad & 1) ? sq[1] : cq[1];
          float f4 = (ytau & 8) ? sq[4] : cq[4];
          float f5 = (ytau & 4) ? sq[5] : cq[5];
          float f6 = (ytau & 2) ? sq[6] : cq[6];
          float f7 = (ytau & 1) ? sq[7] : cq[7];
          float pb = f0 * f1 * f4 * f5 * f6 * f7;
          st[h][0] = pk2(pb * cq[2] * cq[3], 0.f);
          st[h][1] = pk2(pb * cq[2] * sq[3], 0.f);
          st[h][2] = pk2(pb * sq[2] * cq[3], 0.f);
          st[h][3] = pk2(pb * sq[2] * sq[3], 0.f);
        }

#pragma unroll
        for (int t = 0; t < 4; ++t) {
          float4v xr[4], xi[4];
#pragma unroll
          for (int c = 0; c < 4; ++c) {
            half8 A = __builtin_bit_cast(half8, st[c]);
            xr[c] = __builtin_amdgcn_mfma_f32_16x16x32_f16(A, BLR[t], zz, 0, 0, 0);
            xi[c] = __builtin_amdgcn_mfma_f32_16x16x32_f16(A, BLI[t], zz, 0, 0, 0);
          }
          uint4v X[4];
#pragma unroll
          for (int c = 0; c < 4; ++c) {
            X[c][0] = pk2(xr[c][0], xi[c][0]);
            X[c][1] = pk2(xr[c][1], xi[c][1]);
            X[c][2] = pk2(xr[c][2], xi[c][2]);
            X[c][3] = pk2(xr[c][3], xi[c][3]);
          }
          float4v yr[4], yi[4];
#pragma unroll
          for (int c = 0; c < 4; ++c) {
            half8 XA = __builtin_bit_cast(half8, X[c]);
            yr[c] = __builtin_amdgcn_mfma_f32_16x16x32_f16(XA, BRR[t], zz, 0, 0, 0);
            yi[c] = __builtin_amdgcn_mfma_f32_16x16x32_f16(XA, BRI[t], zz, 0, 0, 0);
          }
          if (t < 3) {
#pragma unroll
            for (int c = 0; c < 4; ++c) {
              st[c][0] = pk2(yr[c][0], yi[c][0]);
              st[c][1] = sw8u(pk2(yr[c][1], yi[c][1]));
              st[c][2] = pk2(yr[c][2], yi[c][2]);
              st[c][3] = sw8u(pk2(yr[c][3], yi[c][3]));
            }
          } else {
            MEMFENCE();
#pragma unroll
            for (int c = 0; c < 4; ++c) {
              float r1 = sw8f(yr[c][1]), i1 = sw8f(yi[c][1]);
              float r3 = sw8f(yr[c][3]), i3 = sw8f(yi[c][3]);
              float p0 = yr[c][0] * yr[c][0] + yi[c][0] * yi[c][0];
              float p1 = r1 * r1 + i1 * i1;
              float p2 = yr[c][2] * yr[c][2] + yi[c][2] * yi[c][2];
              float p3 = r3 * r3 + i3 * i3;
              const unsigned e = (unsigned)(4 * i + c);
              unsigned pOff = e * 512u + ((pWg ^ (e & 7u)) << 4) + pWlo;
              uint2v v = { pk2(p0, p1), pk2(p2, p3) };
              *(uint2v*)(smp + pOff) = v;
            }
            MEMFENCE();
          }
        }
      }

      float4v acc = zz;
      MEMFENCE();
#pragma unroll
      for (int c = 0; c < 8; ++c) {
        unsigned pR = (unsigned)(n * 512 +
                                 ((((unsigned)(c * 4 + quad)) ^ (unsigned)(n & 7)) << 4));
        half8 pbv = *(const half8*)(smp + pR);
        acc = __builtin_amdgcn_mfma_f32_16x16x32_f16(sf[c], pbv, acc, 0, 0, 0);
      }
      MEMFENCE();
      if (quad < 2) {
        float4v* o = (float4v*)(out + (size_t)(base + n) * 8 + quad * 4);
        *o = acc;
      }
    }
  }
}

extern "C" void kernel_launch(void* const* d_in, const int* in_sizes, int n_in,
                              void* d_out, int out_size, void* d_ws, size_t ws_size,
                              hipStream_t stream) {
  const float* x = (const float*)d_in[0];
  const float* w = (const float*)d_in[1];
  float* out = (float*)d_out;
  qmain<<<dim3(512), dim3(256), 0, stream>>>(x, w, out);
}

// Round 9
// 83.824 us; speedup vs baseline: 1.0999x; 1.0999x over previous
//
#include <hip/hip_runtime.h>

// QuantumLayer: 8-qubit, 4-layer VQC, state evolution entirely in registers.
// STATE = MFMA A-operand, GATE = B; each pass's C-layout output is exactly the
// next pass's A-fragment (transpose absorbed by alternating passive dim).
// CNOTs 0-2 folded into H~ rows; CNOTs 4-6 (tau) baked into G_R k-order +
// encoding lane labels; CNOT3 residual = dpp lane swap n<->n^8 on odd-u regs.
// ROUND-9 (from r8 counters: VALUBusy 57%, MfmaUtil 28% @ 2 waves/SIMD, VGPR 84,
// no scratch): (a) encoding cross-lane moved from 16 v_readlane (VALU) to 4
// broadcast ds_read_b128 from a per-wave cos/sin LDS table (LDS pipe is idle);
// (b) 4 waves/SIMD via launch_bounds(256,4), grid 1024 x 16 elem/wave (exact
// 4/CU residency, zero tail), ILP2, sf kept in registers, LDS 36864B/block
// (avoids r7's exact-160KiB fit that likely dropped residency).

typedef _Float16 half8  __attribute__((ext_vector_type(8)));
typedef float    float4v __attribute__((ext_vector_type(4)));
typedef float    float2v __attribute__((ext_vector_type(2)));
typedef unsigned int uint2v __attribute__((ext_vector_type(2)));
typedef unsigned int uint4v __attribute__((ext_vector_type(4)));

#define MEMFENCE() __asm__ volatile("" ::: "memory")

__device__ __forceinline__ unsigned pk2(float a, float b) {
  auto v = __builtin_amdgcn_cvt_pkrtz(a, b);
  return __builtin_bit_cast(unsigned, v);
}
__device__ __forceinline__ unsigned sw8u(unsigned v) {
  return (unsigned)__builtin_amdgcn_mov_dpp((int)v, 0x128, 0xf, 0xf, false);
}
__device__ __forceinline__ float sw8f(float v) {
  return __builtin_bit_cast(float,
      __builtin_amdgcn_mov_dpp(__builtin_bit_cast(int, v), 0x128, 0xf, 0xf, false));
}
__device__ __forceinline__ int tauf(int l) {
  int y = l ^ (((l >> 3) & 1) << 2);
  y ^= ((y >> 2) & 1) << 1;
  y ^= (y >> 1) & 1;
  return y;
}

__launch_bounds__(256, 4)
__global__ void qmain(const float* __restrict__ x, const float* __restrict__ w,
                      float* __restrict__ out) {
  // [0,32768): 4 x 8KB per-wave p-buffers (gate staging [0,16384) overlays them
  // before the barrier); [32768,36864): 4 x 1KB per-wave cos/sin tables.
  __shared__ __align__(16) unsigned char smem[36864];
  const int tid = threadIdx.x;
  const int lane = tid & 63, wv = tid >> 6;
  const int quad = lane >> 4, n = lane & 15;

  // ---- phase 0: wave wv builds layer wv's 4 gate B-frags into staging LDS ----
  {
    const int t = wv;
    int mr = n ^ ((n >> 1) & 1);            // P^-1(n): CNOTs 0,1,2 fold
    mr ^= ((mr >> 2) & 1) << 1;
    mr ^= ((mr >> 3) & 1) << 2;
    float cS[8], sS[8], zcS[8], zsS[8];
#pragma unroll
    for (int qq = 0; qq < 8; ++qq) {
      float th = w[(t * 8 + qq) * 2 + 0];
      float tz = w[(t * 8 + qq) * 2 + 1];
      __sincosf(0.5f * th, &sS[qq], &cS[qq]);
      __sincosf(0.5f * tz, &zsS[qq], &zcS[qq]);
    }
    union { _Float16 h[8]; half8 v; } bLR, bLI, bRR, bRI;
#pragma unroll
    for (int ci = 0; ci < 4; ++ci) {
      const int kp = quad * 4 + ci;
      float hr = 1.f, hi = 0.f;              // G_L = H~[n][kp] = H[mr][kp]
#pragma unroll
      for (int j = 0; j < 4; ++j) {
        int rb = (mr >> (3 - j)) & 1, cb = (kp >> (3 - j)) & 1;
        float ryv = (rb == cb) ? cS[j] : (rb ? sS[j] : -sS[j]);
        float ar = zcS[j] * ryv;
        float ai = (rb ? zsS[j] : -zsS[j]) * ryv;
        float nr = hr * ar - hi * ai, ni = hr * ai + hi * ar;
        hr = nr; hi = ni;
      }
      bLR.h[2 * ci] = (_Float16)hr;  bLR.h[2 * ci + 1] = (_Float16)(-hi);
      bLI.h[2 * ci] = (_Float16)hi;  bLI.h[2 * ci + 1] = (_Float16)hr;
      int yk = tauf(kp);                     // G_R = L~[n][tau(kp)]
      float wr = 1.f, wi = 0.f;
#pragma unroll
      for (int j = 0; j < 4; ++j) {
        int rb = (n >> (3 - j)) & 1, cb = (yk >> (3 - j)) & 1;
        float ryv = (rb == cb) ? cS[4 + j] : (rb ? sS[4 + j] : -sS[4 + j]);
        float ar = zcS[4 + j] * ryv;
        float ai = (rb ? zsS[4 + j] : -zsS[4 + j]) * ryv;
        float nr = wr * ar - wi * ai, ni = wr * ai + wi * ar;
        wr = nr; wi = ni;
      }
      bRR.h[2 * ci] = (_Float16)wr;  bRR.h[2 * ci + 1] = (_Float16)(-wi);
      bRI.h[2 * ci] = (_Float16)wi;  bRI.h[2 * ci + 1] = (_Float16)wr;
    }
    half8* FB = (half8*)smem;
    FB[(t * 4 + 0) * 64 + lane] = bLR.v;
    FB[(t * 4 + 1) * 64 + lane] = bLI.v;
    FB[(t * 4 + 2) * 64 + lane] = bRR.v;
    FB[(t * 4 + 3) * 64 + lane] = bRI.v;
  }
  __syncthreads();
  half8 BLR[4], BLI[4], BRR[4], BRI[4];
#pragma unroll
  for (int t = 0; t < 4; ++t) {
    const half8* FB = (const half8*)smem;
    BLR[t] = FB[(t * 4 + 0) * 64 + lane];
    BLI[t] = FB[(t * 4 + 1) * 64 + lane];
    BRR[t] = FB[(t * 4 + 2) * 64 + lane];
    BRI[t] = FB[(t * 4 + 3) * 64 + lane];
  }
  __syncthreads();   // p-buffers may now overlay the staging region

  // ---- sign fragments (registers): A[m=qubit][k=slot]; rows 8-15 zero ----
  half8 sf[8];
#pragma unroll
  for (int c = 0; c < 8; ++c) {
    union { _Float16 h[8]; half8 v; } sg;
#pragma unroll
    for (int jj = 0; jj < 8; ++jj) {
      int u = (quad & 1) * 8 + jj;
      int y = tauf(2 * c + (quad >> 1));
      float sv = 0.f;
      if (n < 8) {
        int bit = (n < 4) ? ((u >> (3 - n)) & 1) : ((y >> (7 - n)) & 1);
        sv = bit ? -1.f : 1.f;
      }
      sg.h[jj] = (_Float16)sv;
    }
    sf[c] = sg.v;
  }

  unsigned char* smp = smem + wv * 8192;            // 16 x 512B p-slots
  unsigned char* cst = smem + 32768 + wv * 1024;    // cos/sin table
  const unsigned pWg = (unsigned)(2 * n + (quad >> 1));
  const unsigned pWlo = (unsigned)((quad & 1) * 8);
  const int e0 = (blockIdx.x * 4 + wv) * 16;
  const float4v zz = {0.f, 0.f, 0.f, 0.f};
  const int ytau = tauf(n);

  // ---- per-wave cos/sin table: lane 8e+q holds element e's qubit-q angle ----
  {
    const float* xp = x + (size_t)e0 * 8;
    float xa = xp[lane], xb = xp[64 + lane];
    float CA, SA, CB, SB;
    __sincosf(0.5f * xa, &SA, &CA);
    __sincosf(0.5f * xb, &SB, &CB);
    MEMFENCE();
    *(float2v*)(cst + lane * 8) = (float2v){CA, SA};        // elems 0-7: bytes 64e+8q
    *(float2v*)(cst + 512 + lane * 8) = (float2v){CB, SB};  // elems 8-15
    MEMFENCE();
  }

#pragma clang loop unroll(disable)
  for (int i = 0; i < 8; ++i) {   // ILP2: elements e = 2i+h
    uint4v st[2];
#pragma unroll
    for (int h = 0; h < 2; ++h) {
      const unsigned ctoff = (unsigned)(2 * i + h) * 64u;
      // 4 broadcast b128 reads (same addr across lanes -> conflict-free)
      float4v t01 = *(const float4v*)(cst + ctoff);        // c0,s0,c1,s1
      float4v t23 = *(const float4v*)(cst + ctoff + 16);   // c2,s2,c3,s3
      float4v t45 = *(const float4v*)(cst + ctoff + 32);   // c4,s4,c5,s5
      float4v t67 = *(const float4v*)(cst + ctoff + 48);   // c6,s6,c7,s7
      float f0 = (quad & 2) ? t01[1] : t01[0];
      float f1 = (quad & 1) ? t01[3] : t01[2];
      float f4 = (ytau & 8) ? t45[1] : t45[0];
      float f5 = (ytau & 4) ? t45[3] : t45[2];
      float f6 = (ytau & 2) ? t67[1] : t67[0];
      float f7 = (ytau & 1) ? t67[3] : t67[2];
      float pb = f0 * f1 * f4 * f5 * f6 * f7;
      float cc = t23[0] * t23[2], cs = t23[0] * t23[3];
      float sc = t23[1] * t23[2], ss = t23[1] * t23[3];
      st[h][0] = pk2(pb * cc, 0.f);
      st[h][1] = pk2(pb * cs, 0.f);
      st[h][2] = pk2(pb * sc, 0.f);
      st[h][3] = pk2(pb * ss, 0.f);
    }

#pragma unroll
    for (int t = 0; t < 4; ++t) {
      // pass L: D1 = S^T * G_L
      float4v xr[2], xi[2];
#pragma unroll
      for (int c = 0; c < 2; ++c) {
        half8 A = __builtin_bit_cast(half8, st[c]);
        xr[c] = __builtin_amdgcn_mfma_f32_16x16x32_f16(A, BLR[t], zz, 0, 0, 0);
        xi[c] = __builtin_amdgcn_mfma_f32_16x16x32_f16(A, BLI[t], zz, 0, 0, 0);
      }
      uint4v X[2];
#pragma unroll
      for (int c = 0; c < 2; ++c) {
        X[c][0] = pk2(xr[c][0], xi[c][0]);
        X[c][1] = pk2(xr[c][1], xi[c][1]);
        X[c][2] = pk2(xr[c][2], xi[c][2]);
        X[c][3] = pk2(xr[c][3], xi[c][3]);
      }
      // pass R: D2 = X * G_R
      float4v yr[2], yi[2];
#pragma unroll
      for (int c = 0; c < 2; ++c) {
        half8 XA = __builtin_bit_cast(half8, X[c]);
        yr[c] = __builtin_amdgcn_mfma_f32_16x16x32_f16(XA, BRR[t], zz, 0, 0, 0);
        yi[c] = __builtin_amdgcn_mfma_f32_16x16x32_f16(XA, BRI[t], zz, 0, 0, 0);
      }
      if (t < 3) {
        // CNOT3 residual: odd-u regs swap lanes n<->n^8
#pragma unroll
        for (int c = 0; c < 2; ++c) {
          st[c][0] = pk2(yr[c][0], yi[c][0]);
          st[c][1] = sw8u(pk2(yr[c][1], yi[c][1]));
          st[c][2] = pk2(yr[c][2], yi[c][2]);
          st[c][3] = sw8u(pk2(yr[c][3], yi[c][3]));
        }
      } else {
        // final CNOT on f32, p = |amp|^2 -> LDS p-buffer
        MEMFENCE();
#pragma unroll
        for (int c = 0; c < 2; ++c) {
          float r1 = sw8f(yr[c][1]), i1 = sw8f(yi[c][1]);
          float r3 = sw8f(yr[c][3]), i3 = sw8f(yi[c][3]);
          float p0 = yr[c][0] * yr[c][0] + yi[c][0] * yi[c][0];
          float p1 = r1 * r1 + i1 * i1;
          float p2 = yr[c][2] * yr[c][2] + yi[c][2] * yi[c][2];
          float p3 = r3 * r3 + i3 * i3;
          const unsigned e = (unsigned)(2 * i + c);
          unsigned pOff = e * 512u + ((pWg ^ (e & 7u)) << 4) + pWlo;
          uint2v v = { pk2(p0, p1), pk2(p2, p3) };
          *(uint2v*)(smp + pOff) = v;
        }
        MEMFENCE();
      }
    }
  }

  // ---- measurement: exps(16 elems x 8 qubits) = Sign(16x256) * P(256x16) ----
  float4v acc = zz;
  MEMFENCE();
#pragma unroll
  for (int c = 0; c < 8; ++c) {
    unsigned pR = (unsigned)(n * 512 +
                             ((((unsigned)(c * 4 + quad)) ^ (unsigned)(n & 7)) << 4));
    half8 pbv = *(const half8*)(smp + pR);
    acc = __builtin_amdgcn_mfma_f32_16x16x32_f16(sf[c], pbv, acc, 0, 0, 0);
  }
  MEMFENCE();
  // C layout: col = n = element, row = quad*4+reg = qubit (rows 8-15 zero)
  if (quad < 2) {
    float4v* o = (float4v*)(out + (size_t)(e0 + n) * 8 + quad * 4);
    *o = acc;
  }
}

extern "C" void kernel_launch(void* const* d_in, const int* in_sizes, int n_in,
                              void* d_out, int out_size, void* d_ws, size_t ws_size,
                              hipStream_t stream) {
  const float* x = (const float*)d_in[0];
  const float* w = (const float*)d_in[1];
  float* out = (float*)d_out;
  qmain<<<dim3(1024), dim3(256), 0, stream>>>(x, w, out);
}

// Round 10
// 75.394 us; speedup vs baseline: 1.2228x; 1.1118x over previous
//
#include <hip/hip_runtime.h>

// QuantumLayer: 8-qubit, 4-layer VQC, state evolution entirely in registers.
// STATE = MFMA A-operand, GATE = B; each pass's C-layout output is exactly the
// next pass's A-fragment. CNOTs 0-2 folded into H~ rows; CNOTs 4-6 (tau) baked
// into G_R k-order + encoding lane labels; CNOT3 residual = dpp swap n<->n^8.
// ROUND-10: r8 revealed r6's ILP4 kernel uses only 84 VGPRs -> its 2-block/CU
// occupancy was GRID-limited, not register-limited (launch_bounds 2nd arg is a
// floor, not a cap). This round = r6 structure VERBATIM (ILP4, sf in regs) at
// grid 1024 x 16 elem/wave -> 4 blocks/CU -> 4 waves/SIMD, plus r9's verified
// encoding-via-broadcast-LDS (moves 16 v_readlane/elem off the VALU pipe).

typedef _Float16 half8  __attribute__((ext_vector_type(8)));
typedef float    float4v __attribute__((ext_vector_type(4)));
typedef float    float2v __attribute__((ext_vector_type(2)));
typedef unsigned int uint2v __attribute__((ext_vector_type(2)));
typedef unsigned int uint4v __attribute__((ext_vector_type(4)));

#define MEMFENCE() __asm__ volatile("" ::: "memory")

__device__ __forceinline__ unsigned pk2(float a, float b) {
  auto v = __builtin_amdgcn_cvt_pkrtz(a, b);
  return __builtin_bit_cast(unsigned, v);
}
__device__ __forceinline__ unsigned sw8u(unsigned v) {
  return (unsigned)__builtin_amdgcn_mov_dpp((int)v, 0x128, 0xf, 0xf, false);
}
__device__ __forceinline__ float sw8f(float v) {
  return __builtin_bit_cast(float,
      __builtin_amdgcn_mov_dpp(__builtin_bit_cast(int, v), 0x128, 0xf, 0xf, false));
}
__device__ __forceinline__ int tauf(int l) {
  int y = l ^ (((l >> 3) & 1) << 2);
  y ^= ((y >> 2) & 1) << 1;
  y ^= (y >> 1) & 1;
  return y;
}

__launch_bounds__(256, 2)   // allocator floor only; actual VGPR ~84 -> 4+ blocks/CU
__global__ void qmain(const float* __restrict__ x, const float* __restrict__ w,
                      float* __restrict__ out) {
  // [0,32768): 4 x 8KB per-wave p-buffers (gate staging [0,16384) overlays
  // before the barrier); [32768,36864): 4 x 1KB per-wave cos/sin tables.
  __shared__ __align__(16) unsigned char smem[36864];
  const int tid = threadIdx.x;
  const int lane = tid & 63, wv = tid >> 6;
  const int quad = lane >> 4, n = lane & 15;

  // ---- phase 0: wave wv builds layer wv's 4 gate B-frags into staging LDS ----
  {
    const int t = wv;
    int mr = n ^ ((n >> 1) & 1);            // P^-1(n): CNOTs 0,1,2 fold
    mr ^= ((mr >> 2) & 1) << 1;
    mr ^= ((mr >> 3) & 1) << 2;
    float cS[8], sS[8], zcS[8], zsS[8];
#pragma unroll
    for (int qq = 0; qq < 8; ++qq) {
      float th = w[(t * 8 + qq) * 2 + 0];
      float tz = w[(t * 8 + qq) * 2 + 1];
      __sincosf(0.5f * th, &sS[qq], &cS[qq]);
      __sincosf(0.5f * tz, &zsS[qq], &zcS[qq]);
    }
    union { _Float16 h[8]; half8 v; } bLR, bLI, bRR, bRI;
#pragma unroll
    for (int ci = 0; ci < 4; ++ci) {
      const int kp = quad * 4 + ci;
      float hr = 1.f, hi = 0.f;              // G_L = H~[n][kp] = H[mr][kp]
#pragma unroll
      for (int j = 0; j < 4; ++j) {
        int rb = (mr >> (3 - j)) & 1, cb = (kp >> (3 - j)) & 1;
        float ryv = (rb == cb) ? cS[j] : (rb ? sS[j] : -sS[j]);
        float ar = zcS[j] * ryv;
        float ai = (rb ? zsS[j] : -zsS[j]) * ryv;
        float nr = hr * ar - hi * ai, ni = hr * ai + hi * ar;
        hr = nr; hi = ni;
      }
      bLR.h[2 * ci] = (_Float16)hr;  bLR.h[2 * ci + 1] = (_Float16)(-hi);
      bLI.h[2 * ci] = (_Float16)hi;  bLI.h[2 * ci + 1] = (_Float16)hr;
      int yk = tauf(kp);                     // G_R = L~[n][tau(kp)]
      float wr = 1.f, wi = 0.f;
#pragma unroll
      for (int j = 0; j < 4; ++j) {
        int rb = (n >> (3 - j)) & 1, cb = (yk >> (3 - j)) & 1;
        float ryv = (rb == cb) ? cS[4 + j] : (rb ? sS[4 + j] : -sS[4 + j]);
        float ar = zcS[4 + j] * ryv;
        float ai = (rb ? zsS[4 + j] : -zsS[4 + j]) * ryv;
        float nr = wr * ar - wi * ai, ni = wr * ai + wi * ar;
        wr = nr; wi = ni;
      }
      bRR.h[2 * ci] = (_Float16)wr;  bRR.h[2 * ci + 1] = (_Float16)(-wi);
      bRI.h[2 * ci] = (_Float16)wi;  bRI.h[2 * ci + 1] = (_Float16)wr;
    }
    half8* FB = (half8*)smem;
    FB[(t * 4 + 0) * 64 + lane] = bLR.v;
    FB[(t * 4 + 1) * 64 + lane] = bLI.v;
    FB[(t * 4 + 2) * 64 + lane] = bRR.v;
    FB[(t * 4 + 3) * 64 + lane] = bRI.v;
  }
  __syncthreads();
  half8 BLR[4], BLI[4], BRR[4], BRI[4];
#pragma unroll
  for (int t = 0; t < 4; ++t) {
    const half8* FB = (const half8*)smem;
    BLR[t] = FB[(t * 4 + 0) * 64 + lane];
    BLI[t] = FB[(t * 4 + 1) * 64 + lane];
    BRR[t] = FB[(t * 4 + 2) * 64 + lane];
    BRI[t] = FB[(t * 4 + 3) * 64 + lane];
  }
  __syncthreads();   // p-buffers may now overlay the staging region

  // ---- sign fragments (registers): A[m=qubit][k=slot]; rows 8-15 zero ----
  half8 sf[8];
#pragma unroll
  for (int c = 0; c < 8; ++c) {
    union { _Float16 h[8]; half8 v; } sg;
#pragma unroll
    for (int jj = 0; jj < 8; ++jj) {
      int u = (quad & 1) * 8 + jj;
      int y = tauf(2 * c + (quad >> 1));
      float sv = 0.f;
      if (n < 8) {
        int bit = (n < 4) ? ((u >> (3 - n)) & 1) : ((y >> (7 - n)) & 1);
        sv = bit ? -1.f : 1.f;
      }
      sg.h[jj] = (_Float16)sv;
    }
    sf[c] = sg.v;
  }

  unsigned char* smp = smem + wv * 8192;            // 16 x 512B p-slots
  unsigned char* cst = smem + 32768 + wv * 1024;    // cos/sin table
  const unsigned pWg = (unsigned)(2 * n + (quad >> 1));
  const unsigned pWlo = (unsigned)((quad & 1) * 8);
  const int e0 = (blockIdx.x * 4 + wv) * 16;
  const float4v zz = {0.f, 0.f, 0.f, 0.f};
  const int ytau = tauf(n);

  // ---- per-wave cos/sin table: entry 8e+q = element e's qubit-q (cos,sin) ----
  {
    const float* xp = x + (size_t)e0 * 8;
    float xa = xp[lane], xb = xp[64 + lane];
    float CA, SA, CB, SB;
    __sincosf(0.5f * xa, &SA, &CA);
    __sincosf(0.5f * xb, &SB, &CB);
    MEMFENCE();
    *(float2v*)(cst + lane * 8) = (float2v){CA, SA};
    *(float2v*)(cst + 512 + lane * 8) = (float2v){CB, SB};
    MEMFENCE();
  }

#pragma unroll
  for (int i = 0; i < 4; ++i) {   // ILP4: elements e = 4i+h, h=0..3
    uint4v st[4];
#pragma unroll
    for (int h = 0; h < 4; ++h) {
      const unsigned ctoff = (unsigned)(4 * i + h) * 64u;
      // 4 broadcast b128 reads (same addr across lanes -> conflict-free)
      float4v t01 = *(const float4v*)(cst + ctoff);        // c0,s0,c1,s1
      float4v t23 = *(const float4v*)(cst + ctoff + 16);   // c2,s2,c3,s3
      float4v t45 = *(const float4v*)(cst + ctoff + 32);   // c4,s4,c5,s5
      float4v t67 = *(const float4v*)(cst + ctoff + 48);   // c6,s6,c7,s7
      float f0 = (quad & 2) ? t01[1] : t01[0];
      float f1 = (quad & 1) ? t01[3] : t01[2];
      float f4 = (ytau & 8) ? t45[1] : t45[0];
      float f5 = (ytau & 4) ? t45[3] : t45[2];
      float f6 = (ytau & 2) ? t67[1] : t67[0];
      float f7 = (ytau & 1) ? t67[3] : t67[2];
      float pb = f0 * f1 * f4 * f5 * f6 * f7;
      st[h][0] = pk2(pb * t23[0] * t23[2], 0.f);
      st[h][1] = pk2(pb * t23[0] * t23[3], 0.f);
      st[h][2] = pk2(pb * t23[1] * t23[2], 0.f);
      st[h][3] = pk2(pb * t23[1] * t23[3], 0.f);
    }

#pragma unroll
    for (int t = 0; t < 4; ++t) {
      // pass L: D1 = S^T * G_L  (16 independent MFMAs across 4 chains)
      float4v xr[4], xi[4];
#pragma unroll
      for (int c = 0; c < 4; ++c) {
        half8 A = __builtin_bit_cast(half8, st[c]);
        xr[c] = __builtin_amdgcn_mfma_f32_16x16x32_f16(A, BLR[t], zz, 0, 0, 0);
        xi[c] = __builtin_amdgcn_mfma_f32_16x16x32_f16(A, BLI[t], zz, 0, 0, 0);
      }
      uint4v X[4];
#pragma unroll
      for (int c = 0; c < 4; ++c) {
        X[c][0] = pk2(xr[c][0], xi[c][0]);
        X[c][1] = pk2(xr[c][1], xi[c][1]);
        X[c][2] = pk2(xr[c][2], xi[c][2]);
        X[c][3] = pk2(xr[c][3], xi[c][3]);
      }
      // pass R: D2 = X * G_R
      float4v yr[4], yi[4];
#pragma unroll
      for (int c = 0; c < 4; ++c) {
        half8 XA = __builtin_bit_cast(half8, X[c]);
        yr[c] = __builtin_amdgcn_mfma_f32_16x16x32_f16(XA, BRR[t], zz, 0, 0, 0);
        yi[c] = __builtin_amdgcn_mfma_f32_16x16x32_f16(XA, BRI[t], zz, 0, 0, 0);
      }
      if (t < 3) {
        // CNOT3 residual: odd-u regs swap lanes n<->n^8
#pragma unroll
        for (int c = 0; c < 4; ++c) {
          st[c][0] = pk2(yr[c][0], yi[c][0]);
          st[c][1] = sw8u(pk2(yr[c][1], yi[c][1]));
          st[c][2] = pk2(yr[c][2], yi[c][2]);
          st[c][3] = sw8u(pk2(yr[c][3], yi[c][3]));
        }
      } else {
        // final CNOT on f32, p = |amp|^2 -> LDS p-buffer
        MEMFENCE();
#pragma unroll
        for (int c = 0; c < 4; ++c) {
          float r1 = sw8f(yr[c][1]), i1 = sw8f(yi[c][1]);
          float r3 = sw8f(yr[c][3]), i3 = sw8f(yi[c][3]);
          float p0 = yr[c][0] * yr[c][0] + yi[c][0] * yi[c][0];
          float p1 = r1 * r1 + i1 * i1;
          float p2 = yr[c][2] * yr[c][2] + yi[c][2] * yi[c][2];
          float p3 = r3 * r3 + i3 * i3;
          const unsigned e = (unsigned)(4 * i + c);
          unsigned pOff = e * 512u + ((pWg ^ (e & 7u)) << 4) + pWlo;
          uint2v v = { pk2(p0, p1), pk2(p2, p3) };
          *(uint2v*)(smp + pOff) = v;
        }
        MEMFENCE();
      }
    }
  }

  // ---- measurement: exps(16 elems x 8 qubits) = Sign(16x256) * P(256x16) ----
  float4v acc = zz;
  MEMFENCE();
#pragma unroll
  for (int c = 0; c < 8; ++c) {
    unsigned pR = (unsigned)(n * 512 +
                             ((((unsigned)(c * 4 + quad)) ^ (unsigned)(n & 7)) << 4));
    half8 pbv = *(const half8*)(smp + pR);
    acc = __builtin_amdgcn_mfma_f32_16x16x32_f16(sf[c], pbv, acc, 0, 0, 0);
  }
  MEMFENCE();
  // C layout: col = n = element, row = quad*4+reg = qubit (rows 8-15 zero)
  if (quad < 2) {
    float4v* o = (float4v*)(out + (size_t)(e0 + n) * 8 + quad * 4);
    *o = acc;
  }
}

extern "C" void kernel_launch(void* const* d_in, const int* in_sizes, int n_in,
                              void* d_out, int out_size, void* d_ws, size_t ws_size,
                              hipStream_t stream) {
  const float* x = (const float*)d_in[0];
  const float* w = (const float*)d_in[1];
  float* out = (float*)d_out;
  qmain<<<dim3(1024), dim3(256), 0, stream>>>(x, w, out);
}